// Round 4
// baseline (890207.422 us; speedup 1.0000x reference)
//
#include <hip/hip_runtime.h>

// LSTM: B=256, T=128, D=64, H=512, 4H=2048, F=256
// Grid: 256 WGs = 16 batch-groups (grp=blockIdx&15) x 16 hidden-slices (slc=blockIdx>>4).
// Per WG: 4 waves, wave w owns 8 hidden units (all 4 gates), full K=512+64.
//   Tile p of wave w: 16 gate-cols {g=2p+(q>>3), u=8w+(q&7)}; D[m=gatecol][n=batch].
// h exchange: per-group, intra-XCD. Runtime XCC_ID handshake picks:
//   FAST: sc0 (SE-scope -> shared XCD L2) loads/stores/flags, ~250cy RTT, no HBM writes.
//   SLOW: agent-scope (IF$) atomics, as r2.
// Sync: per-wave flag words (64/group), wave0 polls lane-parallel, s_barrier release.

#define WH_S 524   // word stride 262 -> bank hop 6 -> <=2-way (free)
#define WX_S 72

typedef __attribute__((ext_vector_type(4))) _Float16 f16x4;
typedef __attribute__((ext_vector_type(4))) float    f32x4;
typedef unsigned long long u64;

struct TrueT  { static constexpr bool value = true;  };
struct FalseT { static constexpr bool value = false; };

__device__ __forceinline__ float sigm(float x)  { return 1.f / (1.f + __expf(-x)); }
__device__ __forceinline__ float tanh_(float x) { float e = __expf(2.f * x); return 1.f - 2.f / (e + 1.f); }

__device__ __forceinline__ u64 ld64_sc0(const u64* p) {
    u64 v; asm volatile("global_load_dwordx2 %0, %1, off sc0" : "=v"(v) : "v"(p)); return v;
}
__device__ __forceinline__ void st64_sc0(u64* p, u64 v) {
    asm volatile("global_store_dwordx2 %0, %1, off sc0" :: "v"(p), "v"(v) : "memory");
}
__device__ __forceinline__ unsigned ldflag_sc0(const unsigned* p) {
    unsigned v;
    asm volatile("global_load_dword %0, %1, off sc0\n\ts_waitcnt vmcnt(0)"
                 : "=v"(v) : "v"(p) : "memory");
    return v;
}
__device__ __forceinline__ void stflag_sc0(unsigned* p, unsigned v) {
    asm volatile("global_store_dword %0, %1, off sc0" :: "v"(p), "v"(v) : "memory");
}

#define MFMA16(w, a, c) __builtin_amdgcn_mfma_f32_16x16x16f16((w), (a), (c), 0, 0, 0)

__launch_bounds__(256, 1)
__global__ void lstm_persist(const float* __restrict__ obs,
                             const float* __restrict__ Wx,
                             const float* __restrict__ Wh,
                             const float* __restrict__ bvec,
                             u64* __restrict__ hbuf,        // [2][256][512] f16 as u64
                             unsigned* __restrict__ flg,    // [16 grp][64] per-wave flags
                             unsigned* __restrict__ xcb)    // [256] xcc-id handshake
{
    __shared__ _Float16 sWh[128 * WH_S];
    __shared__ _Float16 sWx[128 * WX_S];

    const int tid = threadIdx.x, lane = tid & 63, wid = tid >> 6;
    const int grp = blockIdx.x & 15, slc = blockIdx.x >> 4;
    const int l15 = lane & 15, l16 = lane >> 4;

    unsigned xcc;
    asm volatile("s_getreg_b32 %0, hwreg(HW_REG_XCC_ID)" : "=s"(xcc));
    if (tid == 0)
        __hip_atomic_store(xcb + blockIdx.x, xcc + 1u, __ATOMIC_RELAXED, __HIP_MEMORY_SCOPE_AGENT);

    // ---- stage Wh / Wx slices into LDS: col c = w*32 + p*16 + (g&1)*8 + (u&7) ----
    for (int idx = tid; idx < 512 * 128; idx += 256) {
        int k = idx >> 7, c = idx & 127;
        int u = ((c >> 5) << 3) | (c & 7);
        int g = (((c >> 4) & 1) << 1) | ((c >> 3) & 1);
        sWh[c * WH_S + k] = (_Float16)Wh[k * 2048 + (g << 9) + (slc << 5) + u];
    }
    for (int idx = tid; idx < 64 * 128; idx += 256) {
        int k = idx >> 7, c = idx & 127;
        int u = ((c >> 5) << 3) | (c & 7);
        int g = (((c >> 4) & 1) << 1) | ((c >> 3) & 1);
        sWx[c * WX_S + k] = (_Float16)Wx[k * 2048 + (g << 9) + (slc << 5) + u];
    }
    __syncthreads();

    // ---- handshake: are all 16 group members on one XCD? (bounded spin) ----
    unsigned my = xcc + 1u, v;
    int hguard = 0;
    do {
        v = (lane < 16)
            ? __hip_atomic_load(xcb + grp + ((lane & 15) << 4), __ATOMIC_RELAXED, __HIP_MEMORY_SCOPE_AGENT)
            : 1u;
        if (++hguard > (1 << 20)) break;
    } while (!__all((int)(v != 0u)));
    const bool fast = __all((int)((lane < 16) ? (v == my) : 1));

    const int brow = (grp << 4) + l15;                 // batch row (B-frag col / store row)
    const int ub   = (wid << 3) + ((l16 & 1) << 2);    // unit base within 32-slice
    f32x4 bia[4];
    #pragma unroll
    for (int g = 0; g < 4; ++g)
        bia[g] = *(const f32x4*)(bvec + (g << 9) + (slc << 5) + ub);

    const int hload_base = (brow << 7) + l16;                              // + kk*4 (u64)
    const int hstore_idx = (brow << 7) + (slc << 3) + (wid << 1) + (l16 & 1);
    unsigned* const gflg = flg + (grp << 6);
    const int myflag = (slc << 2) + wid;
    const int c0 = (wid << 5) + l15;                   // tile0 LDS col
    const int c1 = c0 + 16;                            // tile1 LDS col

    float c_reg[4] = {0.f, 0.f, 0.f, 0.f};

    auto body = [&](auto FC) {
        constexpr bool F = decltype(FC)::value;
        for (int t = 0; t < 128; ++t) {
            const u64* hc = hbuf + ((t & 1) ? 32768 : 0);
            u64*       hn = hbuf + ((t & 1) ? 0 : 32768);

            if (t) {
                if (wid == 0) {                        // wave0 polls all 64 flags lane-parallel
                    const unsigned tgt = (unsigned)t;
                    unsigned f; int gd = 0;
                    for (;;) {
                        f = F ? ldflag_sc0(gflg + lane)
                              : __hip_atomic_load(gflg + lane, __ATOMIC_RELAXED, __HIP_MEMORY_SCOPE_AGENT);
                        if (__all((int)(f >= tgt))) break;
                        if (++gd > (1 << 16)) break;   // bounded: worst case wrong, never hung
                        __builtin_amdgcn_s_sleep(1);
                    }
                }
                __syncthreads();
                __builtin_amdgcn_sched_barrier(0);
            }

            // obs B-frags (f32 -> f16), compiler-managed cached loads
            f16x4 xf[4];
            const float* op = obs + ((brow << 7) + t) * 64;
            #pragma unroll
            for (int kx = 0; kx < 4; ++kx) {
                f32x4 ov = *(const f32x4*)(op + (kx << 4) + (l16 << 2));
                #pragma unroll
                for (int e = 0; e < 4; ++e) xf[kx][e] = (_Float16)ov[e];
            }

            // h B-frags: 32 x u64, issued back-to-back, one drain
            f16x4 af[32];
            #pragma unroll
            for (int kk = 0; kk < 32; ++kk) {
                u64 r = F ? ld64_sc0(hc + hload_base + (kk << 2))
                          : __hip_atomic_load(hc + hload_base + (kk << 2),
                                              __ATOMIC_RELAXED, __HIP_MEMORY_SCOPE_AGENT);
                af[kk] = __builtin_bit_cast(f16x4, r);
            }
            if (F) { asm volatile("s_waitcnt vmcnt(0)" ::: "memory"); __builtin_amdgcn_sched_barrier(0); }

            // 2 tiles x K=512, parity-split acc chains (4 independent chains)
            f32x4 a00 = {0.f,0.f,0.f,0.f}, a01 = {0.f,0.f,0.f,0.f};
            f32x4 a10 = {0.f,0.f,0.f,0.f}, a11 = {0.f,0.f,0.f,0.f};
            #pragma unroll
            for (int kk = 0; kk < 32; ++kk) {
                f16x4 w0 = *(const f16x4*)(&sWh[c0 * WH_S + (kk << 4) + (l16 << 2)]);
                f16x4 w1 = *(const f16x4*)(&sWh[c1 * WH_S + (kk << 4) + (l16 << 2)]);
                if (kk & 1) { a01 = MFMA16(w0, af[kk], a01); a11 = MFMA16(w1, af[kk], a11); }
                else        { a00 = MFMA16(w0, af[kk], a00); a10 = MFMA16(w1, af[kk], a10); }
            }
            #pragma unroll
            for (int kx = 0; kx < 4; ++kx) {           // fold x_t @ Wx (K=64)
                f16x4 w0 = *(const f16x4*)(&sWx[c0 * WX_S + (kx << 4) + (l16 << 2)]);
                f16x4 w1 = *(const f16x4*)(&sWx[c1 * WX_S + (kx << 4) + (l16 << 2)]);
                a00 = MFMA16(w0, xf[kx], a00);
                a10 = MFMA16(w1, xf[kx], a10);
            }
            f32x4 t0 = a00 + a01, t1 = a10 + a11;      // t0: gate l16>>1; t1: gate 2+(l16>>1)

            // pair exchange lane <-> lane^32: complementary gates, same units
            f32x4 r0, r1;
            #pragma unroll
            for (int rr = 0; rr < 4; ++rr) {
                r0[rr] = __shfl_xor(t0[rr], 32, 64);
                r1[rr] = __shfl_xor(t1[rr], 32, 64);
            }
            const bool low = (l16 < 2);
            f16x4 hv;
            #pragma unroll
            for (int rr = 0; rr < 4; ++rr) {
                float I  = low ? t0[rr] : r0[rr];
                float Fv = low ? r0[rr] : t0[rr];
                float G  = low ? t1[rr] : r1[rr];
                float O  = low ? r1[rr] : t1[rr];
                I  = sigm (I  + bia[0][rr]);
                Fv = sigm (Fv + bia[1][rr]);
                G  = tanh_(G  + bia[2][rr]);
                O  = sigm (O  + bia[3][rr]);
                float cn  = Fv * c_reg[rr] + I * G;
                c_reg[rr] = cn;
                hv[rr] = (_Float16)(O * tanh_(cn));
            }
            if (low) {                                 // 32 lanes/wave store 16b x 8u
                u64 raw = __builtin_bit_cast(u64, hv);
                if (F) st64_sc0(hn + hstore_idx, raw);
                else   __hip_atomic_store(hn + hstore_idx, raw,
                                          __ATOMIC_RELAXED, __HIP_MEMORY_SCOPE_AGENT);
            }
            asm volatile("s_waitcnt vmcnt(0)" ::: "memory");   // h drained before flag
            if (lane == 0) {
                if (F) stflag_sc0(gflg + myflag, (unsigned)(t + 1));
                else   __hip_atomic_store(gflg + myflag, (unsigned)(t + 1),
                                          __ATOMIC_RELAXED, __HIP_MEMORY_SCOPE_AGENT);
            }
        }
    };
    if (fast) body(TrueT{});
    else      body(FalseT{});
}

__launch_bounds__(256)
__global__ void final_proj(const _Float16* __restrict__ hlast,  // [256][512] f16 (hbuf[0])
                           const float* __restrict__ Wd,        // [512][256]
                           const float* __restrict__ bd,        // [256]
                           float* __restrict__ out)             // [256][256]
{
    __shared__ float sh[2048];
    const int tid = threadIdx.x;
    const int rb  = blockIdx.x;
    for (int idx = tid; idx < 2048; idx += 256)
        sh[idx] = (float)hlast[(rb << 2) * 512 + idx];
    __syncthreads();
    float a0 = 0.f, a1 = 0.f, a2 = 0.f, a3 = 0.f;
    for (int k = 0; k < 512; ++k) {
        float w = Wd[(k << 8) + tid];
        a0 += sh[k] * w; a1 += sh[512 + k] * w; a2 += sh[1024 + k] * w; a3 += sh[1536 + k] * w;
    }
    float bb = bd[tid];
    float v0 = a0 + bb, v1 = a1 + bb, v2 = a2 + bb, v3 = a3 + bb;
    out[((rb << 2) + 0) * 256 + tid] = v0 > 0.f ? v0 : 0.f;
    out[((rb << 2) + 1) * 256 + tid] = v1 > 0.f ? v1 : 0.f;
    out[((rb << 2) + 2) * 256 + tid] = v2 > 0.f ? v2 : 0.f;
    out[((rb << 2) + 3) * 256 + tid] = v3 > 0.f ? v3 : 0.f;
}

extern "C" void kernel_launch(void* const* d_in, const int* in_sizes, int n_in,
                              void* d_out, int out_size, void* d_ws, size_t ws_size,
                              hipStream_t stream)
{
    (void)in_sizes; (void)n_in; (void)out_size; (void)ws_size;
    const float* obs = (const float*)d_in[0];
    const float* Wx  = (const float*)d_in[1];
    const float* Wh  = (const float*)d_in[2];
    const float* bv  = (const float*)d_in[3];
    const float* Wd  = (const float*)d_in[4];
    const float* bd  = (const float*)d_in[5];
    float* out = (float*)d_out;

    u64* hbuf      = (u64*)d_ws;                                   // 524288 B
    unsigned* flg  = (unsigned*)((char*)d_ws + 524288);            // 16*64*4 = 4096 B
    unsigned* xcb  = (unsigned*)((char*)d_ws + 524288 + 4096);     // 256*4   = 1024 B

    hipMemsetAsync(d_ws, 0, 524288 + 4096 + 1024, stream);         // h0 + flags + handshake

    void* args[7];
    args[0] = (void*)&obs; args[1] = (void*)&Wx; args[2] = (void*)&Wh;
    args[3] = (void*)&bv;  args[4] = (void*)&hbuf; args[5] = (void*)&flg; args[6] = (void*)&xcb;
    hipError_t e = hipLaunchCooperativeKernel((const void*)lstm_persist,
                                              dim3(256), dim3(256), args, 0, stream);
    if (e != hipSuccess) {
        // 256 WGs x 1 WG/CU (LDS-limited) co-reside on 256 CUs; plain launch is safe.
        lstm_persist<<<dim3(256), dim3(256), 0, stream>>>(obs, Wx, Wh, bv, hbuf, flg, xcb);
    }
    final_proj<<<dim3(64), dim3(256), 0, stream>>>((const _Float16*)d_ws, Wd, bd, out);
}

// Round 5
// 819.365 us; speedup vs baseline: 1086.4597x; 1086.4597x over previous
//
#include <hip/hip_runtime.h>

// LSTM: B=256, T=128, D=64, H=512, 4H=2048, F=256
// Grid: 256 WGs = 16 batch-groups (grp=blockIdx&15) x 16 hidden-slices (slc=blockIdx>>4).
// Per WG: 4 waves; wave w owns 8 hidden units (all 4 gates), full K=512(+64 obs).
//   Tile p of wave w -> 16 gate-cols {g=2p+(q>>3), u=8w+(q&7)}; D[m=gatecol][n=batch].
// h exchange + sync: agent-scope (sc1/IF$) relaxed atomics ONLY — r4 proved sc0 is
//   CU-scope on gfx950 (stores invisible cross-CU until L1 eviction).
// Sync (r2-proven): vmcnt(0) drain -> __syncthreads -> tid0 fetch_add(ctr);
//   next step: each wave polls ctr with one wave-uniform agent load (4 pollers/WG).

#define WH_S 524   // word stride 262 -> bank hop 6 -> <=2-way (free)
#define WX_S 72

typedef __attribute__((ext_vector_type(4))) _Float16 f16x4;
typedef __attribute__((ext_vector_type(4))) float    f32x4;
typedef unsigned long long u64;

__device__ __forceinline__ float sigm(float x)  { return 1.f / (1.f + __expf(-x)); }
__device__ __forceinline__ float tanh_(float x) { float e = __expf(2.f * x); return 1.f - 2.f / (e + 1.f); }

#define MFMA16(w, a, c) __builtin_amdgcn_mfma_f32_16x16x16f16((w), (a), (c), 0, 0, 0)

__launch_bounds__(256, 1)
__global__ void lstm_persist(const float* __restrict__ obs,
                             const float* __restrict__ Wx,
                             const float* __restrict__ Wh,
                             const float* __restrict__ bvec,
                             u64* __restrict__ hbuf,        // [2][256][512] f16 as u64
                             unsigned* __restrict__ bar)    // 16 counters, 64B apart
{
    __shared__ _Float16 sWh[128 * WH_S];
    __shared__ _Float16 sWx[128 * WX_S];

    const int tid = threadIdx.x, lane = tid & 63, wid = tid >> 6;
    const int grp = blockIdx.x & 15, slc = blockIdx.x >> 4;
    const int l15 = lane & 15, l16 = lane >> 4;

    // ---- stage Wh / Wx slices into LDS: col c = w*32 + p*16 + q ----
    // u = 8*(c>>5) + (q&7), g = 2*p + (q>>3)   [HW-verified in r4]
    for (int idx = tid; idx < 512 * 128; idx += 256) {
        int k = idx >> 7, c = idx & 127;
        int u = ((c >> 5) << 3) | (c & 7);
        int g = (((c >> 4) & 1) << 1) | ((c >> 3) & 1);
        sWh[c * WH_S + k] = (_Float16)Wh[k * 2048 + (g << 9) + (slc << 5) + u];
    }
    for (int idx = tid; idx < 64 * 128; idx += 256) {
        int k = idx >> 7, c = idx & 127;
        int u = ((c >> 5) << 3) | (c & 7);
        int g = (((c >> 4) & 1) << 1) | ((c >> 3) & 1);
        sWx[c * WX_S + k] = (_Float16)Wx[k * 2048 + (g << 9) + (slc << 5) + u];
    }
    __syncthreads();

    const int brow = (grp << 4) + l15;                 // batch row (B-frag col)
    const int ub   = (wid << 3) + ((l16 & 1) << 2);    // unit base within 32-slice
    f32x4 bia[4];
    #pragma unroll
    for (int g = 0; g < 4; ++g)
        bia[g] = *(const f32x4*)(bvec + (g << 9) + (slc << 5) + ub);

    const int hload_base = (brow << 7) + l16;                              // + kk*4 (u64)
    const int hstore_idx = (brow << 7) + (slc << 3) + (wid << 1) + (l16 & 1);
    unsigned* const ctr = bar + (grp << 4);
    const int c0 = (wid << 5) + l15;                   // tile0 LDS col (row m = l15)
    const int c1 = c0 + 16;                            // tile1 LDS col

    float c_reg[4] = {0.f, 0.f, 0.f, 0.f};

    for (int t = 0; t < 128; ++t) {
        const u64* hc = hbuf + ((t & 1) ? 32768 : 0);
        u64*       hn = hbuf + ((t & 1) ? 0 : 32768);

        // ---- obs prefetch + cvt: independent of h(t), hides under the spin ----
        f16x4 xf[4];
        const float* op = obs + ((brow << 7) + t) * 64;
        #pragma unroll
        for (int kx = 0; kx < 4; ++kx) {
            f32x4 ov = *(const f32x4*)(op + (kx << 4) + (l16 << 2));
            #pragma unroll
            for (int e = 0; e < 4; ++e) xf[kx][e] = (_Float16)ov[e];
        }

        // ---- wait for all 16 WGs to finish step t-1 (wave-uniform poll) ----
        if (t) {
            const unsigned tgt = (unsigned)(t << 4);
            while (__hip_atomic_load(ctr, __ATOMIC_RELAXED, __HIP_MEMORY_SCOPE_AGENT) < tgt) {}
        }
        __builtin_amdgcn_sched_barrier(0);

        // ---- h B-frags: 32 x u64 agent loads, issued back-to-back ----
        f16x4 af[32];
        #pragma unroll
        for (int kk = 0; kk < 32; ++kk) {
            u64 r = __hip_atomic_load(hc + hload_base + (kk << 2),
                                      __ATOMIC_RELAXED, __HIP_MEMORY_SCOPE_AGENT);
            af[kk] = __builtin_bit_cast(f16x4, r);
        }

        f32x4 a00 = {0.f,0.f,0.f,0.f}, a01 = {0.f,0.f,0.f,0.f};
        f32x4 a10 = {0.f,0.f,0.f,0.f}, a11 = {0.f,0.f,0.f,0.f};

        // Wx MFMAs first: no h dependence, overlaps the h-load latency
        #pragma unroll
        for (int kx = 0; kx < 4; ++kx) {
            f16x4 w0 = *(const f16x4*)(&sWx[c0 * WX_S + (kx << 4) + (l16 << 2)]);
            f16x4 w1 = *(const f16x4*)(&sWx[c1 * WX_S + (kx << 4) + (l16 << 2)]);
            if (kx & 1) { a01 = MFMA16(w0, xf[kx], a01); a11 = MFMA16(w1, xf[kx], a11); }
            else        { a00 = MFMA16(w0, xf[kx], a00); a10 = MFMA16(w1, xf[kx], a10); }
        }
        // Wh MFMAs: 2 tiles x K=512, parity-split chains (4 independent)
        #pragma unroll
        for (int kk = 0; kk < 32; ++kk) {
            f16x4 w0 = *(const f16x4*)(&sWh[c0 * WH_S + (kk << 4) + (l16 << 2)]);
            f16x4 w1 = *(const f16x4*)(&sWh[c1 * WH_S + (kk << 4) + (l16 << 2)]);
            if (kk & 1) { a01 = MFMA16(w0, af[kk], a01); a11 = MFMA16(w1, af[kk], a11); }
            else        { a00 = MFMA16(w0, af[kk], a00); a10 = MFMA16(w1, af[kk], a10); }
        }
        f32x4 t0 = a00 + a01, t1 = a10 + a11;   // t0: gate l16>>1; t1: gate 2+(l16>>1)

        // pair exchange lane <-> lane^32: same units, complementary gates
        f32x4 r0, r1;
        #pragma unroll
        for (int rr = 0; rr < 4; ++rr) {
            r0[rr] = __shfl_xor(t0[rr], 32, 64);
            r1[rr] = __shfl_xor(t1[rr], 32, 64);
        }
        const bool low = (l16 < 2);
        f16x4 hv;
        #pragma unroll
        for (int rr = 0; rr < 4; ++rr) {
            float I  = low ? t0[rr] : r0[rr];
            float Fv = low ? r0[rr] : t0[rr];
            float G  = low ? t1[rr] : r1[rr];
            float O  = low ? r1[rr] : t1[rr];
            I  = sigm (I  + bia[0][rr]);
            Fv = sigm (Fv + bia[1][rr]);
            G  = tanh_(G  + bia[2][rr]);
            O  = sigm (O  + bia[3][rr]);
            float cn  = Fv * c_reg[rr] + I * G;
            c_reg[rr] = cn;
            hv[rr] = (_Float16)(O * tanh_(cn));
        }
        if (low)                                 // 32 lanes/wave store u64 (8 units x 16 batch)
            __hip_atomic_store(hn + hstore_idx, __builtin_bit_cast(u64, hv),
                               __ATOMIC_RELAXED, __HIP_MEMORY_SCOPE_AGENT);

        asm volatile("s_waitcnt vmcnt(0)" ::: "memory");   // own h-stores at IF$
        __syncthreads();                                   // whole WG done + drained
        if (tid == 0)
            __hip_atomic_fetch_add(ctr, 1u, __ATOMIC_RELAXED, __HIP_MEMORY_SCOPE_AGENT);
    }
}

__launch_bounds__(256)
__global__ void final_proj(const _Float16* __restrict__ hlast,  // [256][512] f16 (hbuf[0])
                           const float* __restrict__ Wd,        // [512][256]
                           const float* __restrict__ bd,        // [256]
                           float* __restrict__ out)             // [256][256]
{
    __shared__ float sh[2048];
    const int tid = threadIdx.x;
    const int rb  = blockIdx.x;
    for (int idx = tid; idx < 2048; idx += 256)
        sh[idx] = (float)hlast[(rb << 2) * 512 + idx];
    __syncthreads();
    float a0 = 0.f, a1 = 0.f, a2 = 0.f, a3 = 0.f;
    for (int k = 0; k < 512; ++k) {
        float w = Wd[(k << 8) + tid];
        a0 += sh[k] * w; a1 += sh[512 + k] * w; a2 += sh[1024 + k] * w; a3 += sh[1536 + k] * w;
    }
    float bb = bd[tid];
    float v0 = a0 + bb, v1 = a1 + bb, v2 = a2 + bb, v3 = a3 + bb;
    out[((rb << 2) + 0) * 256 + tid] = v0 > 0.f ? v0 : 0.f;
    out[((rb << 2) + 1) * 256 + tid] = v1 > 0.f ? v1 : 0.f;
    out[((rb << 2) + 2) * 256 + tid] = v2 > 0.f ? v2 : 0.f;
    out[((rb << 2) + 3) * 256 + tid] = v3 > 0.f ? v3 : 0.f;
}

extern "C" void kernel_launch(void* const* d_in, const int* in_sizes, int n_in,
                              void* d_out, int out_size, void* d_ws, size_t ws_size,
                              hipStream_t stream)
{
    (void)in_sizes; (void)n_in; (void)out_size; (void)ws_size;
    const float* obs = (const float*)d_in[0];
    const float* Wx  = (const float*)d_in[1];
    const float* Wh  = (const float*)d_in[2];
    const float* bv  = (const float*)d_in[3];
    const float* Wd  = (const float*)d_in[4];
    const float* bd  = (const float*)d_in[5];
    float* out = (float*)d_out;

    u64* hbuf     = (u64*)d_ws;                                // 2*256*512*2 = 524288 B
    unsigned* bar = (unsigned*)((char*)d_ws + 524288);         // 16 x 64B

    hipMemsetAsync(d_ws, 0, 524288 + 1024, stream);            // zero h0 + counters

    void* args[6];
    args[0] = (void*)&obs; args[1] = (void*)&Wx; args[2] = (void*)&Wh;
    args[3] = (void*)&bv;  args[4] = (void*)&hbuf; args[5] = (void*)&bar;
    hipError_t e = hipLaunchCooperativeKernel((const void*)lstm_persist,
                                              dim3(256), dim3(256), args, 0, stream);
    if (e != hipSuccess) {
        // 256 WGs x 1 WG/CU (LDS-limited) co-reside on 256 CUs; plain launch is safe.
        lstm_persist<<<dim3(256), dim3(256), 0, stream>>>(obs, Wx, Wh, bv, hbuf, bar);
    }
    final_proj<<<dim3(64), dim3(256), 0, stream>>>((const _Float16*)d_ws, Wd, bd, out);
}

// Round 6
// 551.000 us; speedup vs baseline: 1615.6212x; 1.4871x over previous
//
#include <hip/hip_runtime.h>

// LSTM: B=256, T=128, D=64, H=512, 4H=2048, F=256
// Grid: 256 WGs = 16 batch-groups (grp=blockIdx&15) x 16 hidden-slices (slc=blockIdx>>4).
// 4 waves/WG, 1 wave/SIMD: wave w owns 8 hidden units (all gates), full K.
// Weights live in REGISTERS (staged once via LDS). Per step, h(t) is broadcast:
//   each wave 4 coalesced dwordx4 sc0sc1 loads (4 rows) -> LDS tile -> ds_read frags.
// Sync: r2-proven protocol only (drain -> sync -> tid0 fetch_add + sleep-spin -> sync).
// r4 lesson: sc0 alone is CU-scope on gfx950 — all cross-CU data uses sc0+sc1 (IF$).

#define WH_S 524   // staging stride (words 262 -> bank hop 6)
#define WX_S 72
#define HT_S 524   // h-tile row stride in f16 (1048 B: 8B-aligned rows, ~2-way banks)

typedef __attribute__((ext_vector_type(4))) _Float16 f16x4;
typedef __attribute__((ext_vector_type(4))) float    f32x4;
typedef __attribute__((ext_vector_type(2))) unsigned long long u64x2;
typedef unsigned long long u64;

__device__ __forceinline__ float sigm(float x)  { return 1.f / (1.f + __expf(-x)); }
__device__ __forceinline__ float tanh_(float x) { float e = __expf(2.f * x); return 1.f - 2.f / (e + 1.f); }

__device__ __forceinline__ u64x2 ld128_cc(const void* p) {   // agent-coherent 16B load
    u64x2 v;
    asm volatile("global_load_dwordx4 %0, %1, off sc0 sc1" : "=v"(v) : "v"(p));
    return v;
}

#define MFMA16(w, a, c) __builtin_amdgcn_mfma_f32_16x16x16f16((w), (a), (c), 0, 0, 0)

__launch_bounds__(256, 1)
__global__ void lstm_persist(const float* __restrict__ obs,
                             const float* __restrict__ Wx,
                             const float* __restrict__ Wh,
                             const float* __restrict__ bvec,
                             u64* __restrict__ hbuf,        // [2][256][512] f16 as u64
                             unsigned* __restrict__ bar)    // 16 counters, 64B apart
{
    __shared__ _Float16 sbuf[128 * WH_S];   // Wh/Wx staging, then h-tile [16][HT_S]

    const int tid = threadIdx.x, lane = tid & 63, wid = tid >> 6;
    const int grp = blockIdx.x & 15, slc = blockIdx.x >> 4;
    const int l15 = lane & 15, l16 = lane >> 4;
    const int c0 = (wid << 5) + l15, c1 = c0 + 16;

    // ---- stage Wh -> LDS -> register frags (mapping HW-verified r4/r5) ----
    for (int idx = tid; idx < 512 * 128; idx += 256) {
        int k = idx >> 7, c = idx & 127;
        int u = ((c >> 5) << 3) | (c & 7);
        int g = (((c >> 4) & 1) << 1) | ((c >> 3) & 1);
        sbuf[c * WH_S + k] = (_Float16)Wh[k * 2048 + (g << 9) + (slc << 5) + u];
    }
    __syncthreads();
    f16x4 wf0[32], wf1[32];
    #pragma unroll
    for (int kk = 0; kk < 32; ++kk) {
        wf0[kk] = *(const f16x4*)&sbuf[c0 * WH_S + (kk << 4) + (l16 << 2)];
        wf1[kk] = *(const f16x4*)&sbuf[c1 * WH_S + (kk << 4) + (l16 << 2)];
    }
    __syncthreads();
    // ---- stage Wx (reuse buffer) -> register frags ----
    for (int idx = tid; idx < 64 * 128; idx += 256) {
        int k = idx >> 7, c = idx & 127;
        int u = ((c >> 5) << 3) | (c & 7);
        int g = (((c >> 4) & 1) << 1) | ((c >> 3) & 1);
        sbuf[c * WX_S + k] = (_Float16)Wx[k * 2048 + (g << 9) + (slc << 5) + u];
    }
    __syncthreads();
    f16x4 xw0[4], xw1[4];
    #pragma unroll
    for (int kx = 0; kx < 4; ++kx) {
        xw0[kx] = *(const f16x4*)&sbuf[c0 * WX_S + (kx << 4) + (l16 << 2)];
        xw1[kx] = *(const f16x4*)&sbuf[c1 * WX_S + (kx << 4) + (l16 << 2)];
    }
    __syncthreads();
    _Float16* const sh = sbuf;                         // h-tile [16][HT_S] from here on

    const int brow = (grp << 4) + l15;                 // B-frag batch row
    const int ub   = (wid << 3) + ((l16 & 1) << 2);
    f32x4 bia[4];
    #pragma unroll
    for (int g = 0; g < 4; ++g)
        bia[g] = *(const f32x4*)(bvec + (g << 9) + (slc << 5) + ub);

    const int r_ld  = (wid << 2) + (lane >> 4);        // row this lane stages (0..15)
    const int ch16  = lane & 15;                       // 16B-chunk index
    const int hstore_idx = (brow << 7) + (slc << 3) + (wid << 1) + (l16 & 1);
    unsigned* const ctr = bar + (grp << 4);

    float c_reg[4] = {0.f, 0.f, 0.f, 0.f};

    for (int t = 0; t < 128; ++t) {
        const u64* hc = hbuf + ((t & 1) ? 32768 : 0);
        u64*       hn = hbuf + ((t & 1) ? 0 : 32768);

        // ---- cooperative h(t) broadcast: 4 coalesced 16B sc0sc1 loads/wave ----
        const u64* hrow = hc + (((grp << 4) + r_ld) << 7) + (ch16 << 1);
        u64x2 hv4[4];
        #pragma unroll
        for (int j = 0; j < 4; ++j) hv4[j] = ld128_cc(hrow + (j << 5));

        // obs frags (plain cached loads) + cvt
        f16x4 xf[4];
        const float* op = obs + ((brow << 7) + t) * 64;
        #pragma unroll
        for (int kx = 0; kx < 4; ++kx) {
            f32x4 ov = *(const f32x4*)(op + (kx << 4) + (l16 << 2));
            #pragma unroll
            for (int e = 0; e < 4; ++e) xf[kx][e] = (_Float16)ov[e];
        }

        asm volatile("s_waitcnt vmcnt(0)" ::: "memory");   // h loads returned
        #pragma unroll
        for (int j = 0; j < 4; ++j) {                      // LDS tile write (8B-aligned)
            *(u64*)&sh[r_ld * HT_S + (j << 7) + (ch16 << 3)]     = hv4[j][0];
            *(u64*)&sh[r_ld * HT_S + (j << 7) + (ch16 << 3) + 4] = hv4[j][1];
        }
        __syncthreads();

        f32x4 a00 = {0.f,0.f,0.f,0.f}, a01 = {0.f,0.f,0.f,0.f};
        f32x4 a10 = {0.f,0.f,0.f,0.f}, a11 = {0.f,0.f,0.f,0.f};

        // Wx MFMAs first (pure-reg) while af ds_reads stream in
        #pragma unroll
        for (int kx = 0; kx < 4; ++kx) {
            if (kx & 1) { a01 = MFMA16(xw0[kx], xf[kx], a01); a11 = MFMA16(xw1[kx], xf[kx], a11); }
            else        { a00 = MFMA16(xw0[kx], xf[kx], a00); a10 = MFMA16(xw1[kx], xf[kx], a10); }
        }
        #pragma unroll
        for (int kk = 0; kk < 32; ++kk) {
            f16x4 af = *(const f16x4*)&sh[l15 * HT_S + (kk << 4) + (l16 << 2)];
            if (kk & 1) { a01 = MFMA16(wf0[kk], af, a01); a11 = MFMA16(wf1[kk], af, a11); }
            else        { a00 = MFMA16(wf0[kk], af, a00); a10 = MFMA16(wf1[kk], af, a10); }
        }
        f32x4 t0 = a00 + a01, t1 = a10 + a11;   // t0: gate l16>>1; t1: gate 2+(l16>>1)

        // pair exchange lane <-> lane^32: same units, complementary gates (r5-verified)
        f32x4 r0, r1;
        #pragma unroll
        for (int rr = 0; rr < 4; ++rr) {
            r0[rr] = __shfl_xor(t0[rr], 32, 64);
            r1[rr] = __shfl_xor(t1[rr], 32, 64);
        }
        const bool low = (l16 < 2);
        f16x4 hv;
        #pragma unroll
        for (int rr = 0; rr < 4; ++rr) {
            float I  = low ? t0[rr] : r0[rr];
            float Fv = low ? r0[rr] : t0[rr];
            float G  = low ? t1[rr] : r1[rr];
            float O  = low ? r1[rr] : t1[rr];
            I  = sigm (I  + bia[0][rr]);
            Fv = sigm (Fv + bia[1][rr]);
            G  = tanh_(G  + bia[2][rr]);
            O  = sigm (O  + bia[3][rr]);
            float cn  = Fv * c_reg[rr] + I * G;
            c_reg[rr] = cn;
            hv[rr] = (_Float16)(O * tanh_(cn));
        }
        if (low)                                 // 32 lanes/wave store u64 (8 units x 16 batch)
            __hip_atomic_store(hn + hstore_idx, __builtin_bit_cast(u64, hv),
                               __ATOMIC_RELAXED, __HIP_MEMORY_SCOPE_AGENT);

        if (t < 127) {                           // r2-proven group barrier
            asm volatile("s_waitcnt vmcnt(0)" ::: "memory");   // own h-stores at IF$
            __syncthreads();
            if (tid == 0) {
                __hip_atomic_fetch_add(ctr, 1u, __ATOMIC_RELAXED, __HIP_MEMORY_SCOPE_AGENT);
                const unsigned tgt = (unsigned)((t + 1) << 4);
                while (__hip_atomic_load(ctr, __ATOMIC_RELAXED, __HIP_MEMORY_SCOPE_AGENT) < tgt)
                    __builtin_amdgcn_s_sleep(1);
            }
            __syncthreads();
        }
    }
}

__launch_bounds__(256)
__global__ void final_proj(const _Float16* __restrict__ hlast,  // [256][512] f16 (hbuf[0])
                           const float* __restrict__ Wd,        // [512][256]
                           const float* __restrict__ bd,        // [256]
                           float* __restrict__ out)             // [256][256]
{
    __shared__ float shm[2048];
    const int tid = threadIdx.x;
    const int rb  = blockIdx.x;
    for (int idx = tid; idx < 2048; idx += 256)
        shm[idx] = (float)hlast[(rb << 2) * 512 + idx];
    __syncthreads();
    float a0 = 0.f, a1 = 0.f, a2 = 0.f, a3 = 0.f;
    for (int k = 0; k < 512; ++k) {
        float w = Wd[(k << 8) + tid];
        a0 += shm[k] * w; a1 += shm[512 + k] * w; a2 += shm[1024 + k] * w; a3 += shm[1536 + k] * w;
    }
    float bb = bd[tid];
    float v0 = a0 + bb, v1 = a1 + bb, v2 = a2 + bb, v3 = a3 + bb;
    out[((rb << 2) + 0) * 256 + tid] = v0 > 0.f ? v0 : 0.f;
    out[((rb << 2) + 1) * 256 + tid] = v1 > 0.f ? v1 : 0.f;
    out[((rb << 2) + 2) * 256 + tid] = v2 > 0.f ? v2 : 0.f;
    out[((rb << 2) + 3) * 256 + tid] = v3 > 0.f ? v3 : 0.f;
}

extern "C" void kernel_launch(void* const* d_in, const int* in_sizes, int n_in,
                              void* d_out, int out_size, void* d_ws, size_t ws_size,
                              hipStream_t stream)
{
    (void)in_sizes; (void)n_in; (void)out_size; (void)ws_size;
    const float* obs = (const float*)d_in[0];
    const float* Wx  = (const float*)d_in[1];
    const float* Wh  = (const float*)d_in[2];
    const float* bv  = (const float*)d_in[3];
    const float* Wd  = (const float*)d_in[4];
    const float* bd  = (const float*)d_in[5];
    float* out = (float*)d_out;

    u64* hbuf     = (u64*)d_ws;                                // 2*256*512*2 = 524288 B
    unsigned* bar = (unsigned*)((char*)d_ws + 524288);         // 16 x 64B

    hipMemsetAsync(d_ws, 0, 524288 + 1024, stream);            // zero h0 + counters

    void* args[6];
    args[0] = (void*)&obs; args[1] = (void*)&Wx; args[2] = (void*)&Wh;
    args[3] = (void*)&bv;  args[4] = (void*)&hbuf; args[5] = (void*)&bar;
    hipError_t e = hipLaunchCooperativeKernel((const void*)lstm_persist,
                                              dim3(256), dim3(256), args, 0, stream);
    if (e != hipSuccess) {
        // 256 WGs x 1 WG/CU co-reside on 256 CUs; plain launch is safe.
        lstm_persist<<<dim3(256), dim3(256), 0, stream>>>(obs, Wx, Wh, bv, hbuf, bar);
    }
    final_proj<<<dim3(64), dim3(256), 0, stream>>>((const _Float16*)d_ws, Wd, bd, out);
}